// Round 1
// baseline (327.034 us; speedup 1.0000x reference)
//
#include <hip/hip_runtime.h>

#define HH 128
#define NN 64
#define LL 256
#define LP 512
#define BB 2

// Generate concatenated bidirectional SSM kernel per head:
// kcat[h][256+d] = kf[d] (d>=0), kcat[h][255-d'] = kb[d'].
// channel 0 (c==0) -> forward taps at [256+l]; channel 1 -> backward taps at [255-l].
__global__ __launch_bounds__(256) void ssm_gen(
    const float* __restrict__ A_re, const float* __restrict__ A_im,
    const float* __restrict__ C_re, const float* __restrict__ C_im,
    const float* __restrict__ log_dt, float* __restrict__ kcat)
{
    int l = threadIdx.x;     // 0..255
    int h = blockIdx.x;      // 0..127
    int c = blockIdx.y;      // 0..1
    float dt = expf(log_dt[h]);
    float acc = 0.f;
    for (int n = 0; n < NN; ++n) {
        float ar = A_re[h*NN + n], ai = A_im[h*NN + n];
        float cr = C_re[(c*HH + h)*NN + n], ci = C_im[(c*HH + h)*NN + n];
        float xr = dt * ar, xi = dt * ai;
        // exp(dtA) - 1
        float e = expf(xr);
        float sn, cs; sincosf(xi, &sn, &cs);
        float er = e*cs - 1.f, ei = e*sn;
        // (exp(dtA)-1)/A  = num * conj(A) / |A|^2
        float inv = 1.f / (ar*ar + ai*ai);
        float dr = (er*ar + ei*ai) * inv;
        float di = (ei*ar - er*ai) * inv;
        // K = C * d
        float Kr = cr*dr - ci*di;
        float Ki = cr*di + ci*dr;
        // vand(l) = exp(dtA * l)
        float mag = expf(xr * (float)l);
        float s2, c2; sincosf(xi * (float)l, &s2, &c2);
        acc += Kr*(mag*c2) - Ki*(mag*s2);
    }
    int idx = (c == 0) ? (256 + l) : (255 - l);
    kcat[h*LP + idx] = 2.f * acc;
}

// Pass 1: convolve along axis L1 (index t over rows).
// v[b,h,t,j] = sum_s kcat1[h][256+t-s] * u[b,h,s,j]
// tile: 64 t x 128 j per block; 256 threads.
__global__ __launch_bounds__(256) void conv1(
    const float* __restrict__ u, const float* __restrict__ kcat,
    float* __restrict__ v)
{
    __shared__ float sk[LP];
    __shared__ float su[32][128];
    int bh = blockIdx.y;                 // b*H + h
    int h  = bh & (HH - 1);
    int t0 = (blockIdx.x >> 1) * 64;
    int j0 = (blockIdx.x & 1) * 128;
    int tid = threadIdx.x;

    sk[tid]       = kcat[h*LP + tid];
    sk[tid + 256] = kcat[h*LP + tid + 256];

    const float* ub = u + (size_t)bh * LL * LL;
    float acc[16][2];
#pragma unroll
    for (int i = 0; i < 16; ++i) { acc[i][0] = 0.f; acc[i][1] = 0.f; }

    int lane = tid & 63;
    int tq   = tid >> 6;      // 0..3
    int col  = tid & 127;
    int rg   = tid >> 7;      // 0..1

    for (int s0 = 0; s0 < LL; s0 += 32) {
        __syncthreads();
#pragma unroll
        for (int r = 0; r < 16; ++r)
            su[rg*16 + r][col] = ub[(size_t)(s0 + rg*16 + r)*LL + j0 + col];
        __syncthreads();
        for (int ss = 0; ss < 32; ++ss) {
            int s = s0 + ss;
            float u0 = su[ss][lane];
            float u1 = su[ss][lane + 64];
#pragma unroll
            for (int tt = 0; tt < 16; ++tt) {
                int t = t0 + tq*16 + tt;
                float m = sk[256 + t - s];   // wave-uniform broadcast
                acc[tt][0] += m * u0;
                acc[tt][1] += m * u1;
            }
        }
    }
    float* vb = v + (size_t)bh * LL * LL;
#pragma unroll
    for (int tt = 0; tt < 16; ++tt) {
        int t = t0 + tq*16 + tt;
        vb[(size_t)t*LL + j0 + lane]      = acc[tt][0];
        vb[(size_t)t*LL + j0 + lane + 64] = acc[tt][1];
    }
}

// Pass 2: convolve along axis L2 (last axis) + D*u epilogue.
// y[b,h,i,t] = sum_s kcat2[h][256+t-s] * v[b,h,i,s] + D[h]*u[b,h,i,t]
// tile: 64 i x 128 t per block; 256 threads.
__global__ __launch_bounds__(256) void conv2(
    const float* __restrict__ v, const float* __restrict__ u,
    const float* __restrict__ kcat, const float* __restrict__ Dv,
    float* __restrict__ y)
{
    __shared__ float sk[LP];
    __shared__ float sv[64][32];
    int bh = blockIdx.y;
    int h  = bh & (HH - 1);
    int i0 = (blockIdx.x >> 1) * 64;
    int t0 = (blockIdx.x & 1) * 128;
    int tid = threadIdx.x;

    sk[tid]       = kcat[h*LP + tid];
    sk[tid + 256] = kcat[h*LP + tid + 256];

    const float* vb = v + (size_t)bh * LL * LL;
    float acc[16][2];
#pragma unroll
    for (int i = 0; i < 16; ++i) { acc[i][0] = 0.f; acc[i][1] = 0.f; }

    int lane = tid & 63;
    int iq   = tid >> 6;     // 0..3
    int sIdx = tid & 31;
    int iIdx = tid >> 5;     // 0..7

    for (int s0 = 0; s0 < LL; s0 += 32) {
        __syncthreads();
#pragma unroll
        for (int r = 0; r < 8; ++r)
            sv[iIdx*8 + r][sIdx] = vb[(size_t)(i0 + iIdx*8 + r)*LL + s0 + sIdx];
        __syncthreads();
        for (int ss = 0; ss < 32; ++ss) {
            int s = s0 + ss;
            // per-lane consecutive gather: conflict-free
            float m0 = sk[256 + t0 + lane - s];
            float m1 = sk[256 + t0 + 64 + lane - s];
#pragma unroll
            for (int ii = 0; ii < 16; ++ii) {
                float vv = sv[iq*16 + ii][ss];   // broadcast
                acc[ii][0] += m0 * vv;
                acc[ii][1] += m1 * vv;
            }
        }
    }
    const float* ub = u + (size_t)bh * LL * LL;
    float* yb = y + (size_t)bh * LL * LL;
    float dh = Dv[h];
#pragma unroll
    for (int ii = 0; ii < 16; ++ii) {
        int i = i0 + iq*16 + ii;
        yb[(size_t)i*LL + t0 + lane]      = acc[ii][0] + dh * ub[(size_t)i*LL + t0 + lane];
        yb[(size_t)i*LL + t0 + lane + 64] = acc[ii][1] + dh * ub[(size_t)i*LL + t0 + lane + 64];
    }
}

extern "C" void kernel_launch(void* const* d_in, const int* in_sizes, int n_in,
                              void* d_out, int out_size, void* d_ws, size_t ws_size,
                              hipStream_t stream)
{
    const float* u       = (const float*)d_in[0];
    const float* D       = (const float*)d_in[1];
    const float* A_re0   = (const float*)d_in[2];
    const float* A_im0   = (const float*)d_in[3];
    const float* C_re0   = (const float*)d_in[4];
    const float* C_im0   = (const float*)d_in[5];
    const float* log_dt0 = (const float*)d_in[6];
    const float* A_re1   = (const float*)d_in[7];
    const float* A_im1   = (const float*)d_in[8];
    const float* C_re1   = (const float*)d_in[9];
    const float* C_im1   = (const float*)d_in[10];
    const float* log_dt1 = (const float*)d_in[11];
    float* out = (float*)d_out;

    float* ws    = (float*)d_ws;
    float* kcat1 = ws;                    // H*512 floats
    float* kcat2 = ws + HH*LP;            // H*512 floats
    float* v     = ws + 2*HH*LP;          // B*H*256*256 floats

    ssm_gen<<<dim3(HH, 2), 256, 0, stream>>>(A_re0, A_im0, C_re0, C_im0, log_dt0, kcat1);
    ssm_gen<<<dim3(HH, 2), 256, 0, stream>>>(A_re1, A_im1, C_re1, C_im1, log_dt1, kcat2);
    conv1<<<dim3(8, BB*HH), 256, 0, stream>>>(u, kcat1, v);
    conv2<<<dim3(8, BB*HH), 256, 0, stream>>>(v, u, kcat2, D, out);
}

// Round 3
// 142.822 us; speedup vs baseline: 2.2898x; 2.2898x over previous
//
#include <hip/hip_runtime.h>

#define HH 128
#define NN 64
#define LL 256
#define LP 512

typedef __attribute__((ext_vector_type(8))) short bf8;
typedef __attribute__((ext_vector_type(4))) float f32x4;

__device__ inline ushort f2bf(float f) {
    uint x = __float_as_uint(f);
    return (ushort)((x + 0x7fffu + ((x >> 16) & 1u)) >> 16);
}

// Generate concatenated bidirectional SSM kernel per head, bf16 output.
// kcat[h][256+d] = kf[d] (d>=0); kcat[h][255-l] = kb[l].
__global__ __launch_bounds__(256) void ssm_gen(
    const float* __restrict__ A_re, const float* __restrict__ A_im,
    const float* __restrict__ C_re, const float* __restrict__ C_im,
    const float* __restrict__ log_dt, ushort* __restrict__ kcat)
{
    int l = threadIdx.x;
    int h = blockIdx.x;
    int c = blockIdx.y;
    float dt = expf(log_dt[h]);
    float acc = 0.f;
    for (int n = 0; n < NN; ++n) {
        float ar = A_re[h*NN + n], ai = A_im[h*NN + n];
        float cr = C_re[(c*HH + h)*NN + n], ci = C_im[(c*HH + h)*NN + n];
        float xr = dt * ar, xi = dt * ai;
        float e = expf(xr);
        float sn, cs; sincosf(xi, &sn, &cs);
        float er = e*cs - 1.f, ei = e*sn;
        float inv = 1.f / (ar*ar + ai*ai);
        float dr = (er*ar + ei*ai) * inv;
        float di = (ei*ar - er*ai) * inv;
        float Kr = cr*dr - ci*di;
        float Ki = cr*di + ci*dr;
        float mag = expf(xr * (float)l);
        float s2, c2; sincosf(xi * (float)l, &s2, &c2);
        acc += Kr*(mag*c2) - Ki*(mag*s2);
    }
    int idx = (c == 0) ? (256 + l) : (255 - l);
    kcat[h*LP + idx] = f2bf(2.f * acc);
}

// Pass A (y-axis conv): WT[y'][x] = sum_y kcat2[256+y'-y] * U[x][y]
// A = M2 (Toeplitz, generated), B = U (natural row-major). Output written
// bf16 to xk-blocked layout wt[bh][xk=x/32][y'][x%32] via LDS shuffle.
__global__ __launch_bounds__(256) void convY(
    const float* __restrict__ u, const ushort* __restrict__ kcat2,
    ushort* __restrict__ wt)
{
    __shared__ ushort smem[128*136];                     // epilogue view [128][136]
    ushort (*sM)[40] = (ushort(*)[40])smem;              // [128][40]  M2 tile
    ushort (*sB)[40] = (ushort(*)[40])(smem + 128*40);   // [128][40]  U tile
    __shared__ ushort skc[LP];

    int bh = blockIdx.y;
    int h  = bh & (HH-1);
    int ty = blockIdx.x >> 1, tx = blockIdx.x & 1;
    int y0 = ty*128, x0 = tx*128;
    int tid = threadIdx.x;

    skc[tid]       = kcat2[h*LP + tid];
    skc[tid + 256] = kcat2[h*LP + 256 + tid];

    const float* ub = u + (size_t)bh*LL*LL;

    int lane = tid & 63;
    int w = tid >> 6;
    int wy = (w>>1)*64, wx = (w&1)*64;
    int c = lane & 15, q = lane >> 4;

    int gr  = tid >> 1;            // M-gen row 0..127
    int ghf = (tid & 1) * 16;      // M-gen half
    int ur  = tid >> 3;            // U-stage row 0..31
    int uy  = (tid & 7) * 4;       // U-stage col

    f32x4 acc[4][4];
#pragma unroll
    for (int m = 0; m < 4; ++m)
#pragma unroll
        for (int n = 0; n < 4; ++n)
            acc[m][n] = (f32x4){0.f, 0.f, 0.f, 0.f};

    for (int kk = 0; kk < 8; ++kk) {
        int yb = kk*32;
        __syncthreads();
        // stage U tile [128 x][32 y] fp32 -> bf16
#pragma unroll
        for (int rr = 0; rr < 4; ++rr) {
            int xr = ur + 32*rr;
            float4 uv = *(const float4*)(ub + (size_t)(x0+xr)*LL + yb + uy);
            uint p0 = (uint)f2bf(uv.x) | ((uint)f2bf(uv.y) << 16);
            uint p1 = (uint)f2bf(uv.z) | ((uint)f2bf(uv.w) << 16);
            *(uint*)&sB[xr][uy]     = p0;
            *(uint*)&sB[xr][uy + 2] = p1;
        }
        // generate M2 tile: sM[r][yy] = skc[256 + y0+r - yb - yy]
        {
            int base = 256 + y0 + gr - yb - ghf;
#pragma unroll
            for (int j = 0; j < 8; ++j) {
                uint lo = skc[base - 2*j];
                uint hi = skc[base - 2*j - 1];
                *(uint*)&sM[gr][ghf + 2*j] = lo | (hi << 16);
            }
        }
        __syncthreads();
        bf8 a[4], b[4];
#pragma unroll
        for (int m = 0; m < 4; ++m)
            a[m] = *(const bf8*)&sM[wy + 16*m + c][8*q];
#pragma unroll
        for (int n = 0; n < 4; ++n)
            b[n] = *(const bf8*)&sB[wx + 16*n + c][8*q];
#pragma unroll
        for (int m = 0; m < 4; ++m)
#pragma unroll
            for (int n = 0; n < 4; ++n)
                acc[m][n] = __builtin_amdgcn_mfma_f32_16x16x32_bf16(a[m], b[n], acc[m][n], 0, 0, 0);
    }

    // epilogue: acc -> bf16 LDS tile -> coalesced blocked global store
    __syncthreads();
    ushort (*ep)[136] = (ushort(*)[136])smem;
#pragma unroll
    for (int m = 0; m < 4; ++m)
#pragma unroll
        for (int n = 0; n < 4; ++n)
#pragma unroll
            for (int r = 0; r < 4; ++r)
                ep[wy + 16*m + 4*q + r][wx + 16*n + c] = f2bf(acc[m][n][r]);
    __syncthreads();

    ushort* wb = wt + (size_t)bh*8*LL*32;
#pragma unroll
    for (int it = 0; it < 8; ++it) {
        int e = tid + 256*it;
        int row = e >> 4;
        int ch  = e & 15;
        int xk  = tx*4 + (ch >> 2);
        int xi  = (ch & 3) * 8;
        *(uint4*)(wb + ((size_t)(xk*LL) + y0 + row)*32 + xi) =
            *(const uint4*)&ep[row][ch*8];
    }
}

// Pass B (x-axis conv): Y[x'][y'] = sum_x kcat1[256+x'-x] * WT[y'][x]  (+ D*u)
// A = M1 (generated), B = WT (blocked layout, k-step kk == xk block kk).
__global__ __launch_bounds__(256) void convX(
    const ushort* __restrict__ wt, const float* __restrict__ u,
    const ushort* __restrict__ kcat1, const float* __restrict__ Dv,
    float* __restrict__ out)
{
    __shared__ ushort sM[128][40];
    __shared__ ushort sB[128][40];
    __shared__ ushort skc[LP];

    int bh = blockIdx.y;
    int h  = bh & (HH-1);
    int tX = blockIdx.x >> 1, tY = blockIdx.x & 1;
    int xp0 = tX*128, yp0 = tY*128;
    int tid = threadIdx.x;

    skc[tid]       = kcat1[h*LP + tid];
    skc[tid + 256] = kcat1[h*LP + 256 + tid];

    int lane = tid & 63;
    int w = tid >> 6;
    int wm = (w>>1)*64, wn = (w&1)*64;
    int c = lane & 15, q = lane >> 4;

    int gr  = tid >> 1;
    int ghf = (tid & 1) * 16;

    f32x4 acc[4][4];
#pragma unroll
    for (int m = 0; m < 4; ++m)
#pragma unroll
        for (int n = 0; n < 4; ++n)
            acc[m][n] = (f32x4){0.f, 0.f, 0.f, 0.f};

    const ushort* wbh = wt + (size_t)bh*8*LL*32;

    for (int kk = 0; kk < 8; ++kk) {
        int xb = kk*32;
        __syncthreads();
        // stage WT tile: linear 8KB block -> padded LDS
        const ushort* wsrc = wbh + ((size_t)kk*LL + yp0)*32;
#pragma unroll
        for (int it = 0; it < 2; ++it) {
            int e = tid + 256*it;
            int row = e >> 2;
            int xi  = (e & 3) * 8;
            *(uint4*)&sB[row][xi] = *(const uint4*)(wsrc + e*8);
        }
        // generate M1 tile: sM[r][xx] = skc[256 + xp0+r - xb - xx]
        {
            int base = 256 + xp0 + gr - xb - ghf;
#pragma unroll
            for (int j = 0; j < 8; ++j) {
                uint lo = skc[base - 2*j];
                uint hi = skc[base - 2*j - 1];
                *(uint*)&sM[gr][ghf + 2*j] = lo | (hi << 16);
            }
        }
        __syncthreads();
        bf8 a[4], b[4];
#pragma unroll
        for (int m = 0; m < 4; ++m)
            a[m] = *(const bf8*)&sM[wm + 16*m + c][8*q];
#pragma unroll
        for (int n = 0; n < 4; ++n)
            b[n] = *(const bf8*)&sB[wn + 16*n + c][8*q];
#pragma unroll
        for (int m = 0; m < 4; ++m)
#pragma unroll
            for (int n = 0; n < 4; ++n)
                acc[m][n] = __builtin_amdgcn_mfma_f32_16x16x32_bf16(a[m], b[n], acc[m][n], 0, 0, 0);
    }

    float dh = Dv[h];
    const float* ub = u + (size_t)bh*LL*LL;
    float* yb = out + (size_t)bh*LL*LL;
#pragma unroll
    for (int m = 0; m < 4; ++m)
#pragma unroll
        for (int n = 0; n < 4; ++n)
#pragma unroll
            for (int r = 0; r < 4; ++r) {
                int row = xp0 + wm + 16*m + 4*q + r;
                int col = yp0 + wn + 16*n + c;
                size_t o = (size_t)row*LL + col;
                yb[o] = acc[m][n][r] + dh * ub[o];
            }
}

extern "C" void kernel_launch(void* const* d_in, const int* in_sizes, int n_in,
                              void* d_out, int out_size, void* d_ws, size_t ws_size,
                              hipStream_t stream)
{
    const float* u       = (const float*)d_in[0];
    const float* D       = (const float*)d_in[1];
    const float* A_re0   = (const float*)d_in[2];
    const float* A_im0   = (const float*)d_in[3];
    const float* C_re0   = (const float*)d_in[4];
    const float* C_im0   = (const float*)d_in[5];
    const float* log_dt0 = (const float*)d_in[6];
    const float* A_re1   = (const float*)d_in[7];
    const float* A_im1   = (const float*)d_in[8];
    const float* C_re1   = (const float*)d_in[9];
    const float* C_im1   = (const float*)d_in[10];
    const float* log_dt1 = (const float*)d_in[11];
    float* out = (float*)d_out;

    ushort* kc1 = (ushort*)d_ws;          // 128*512
    ushort* kc2 = kc1 + HH*LP;            // 128*512
    ushort* wtb = kc2 + HH*LP;            // 256*8*256*32 bf16 = 33.5 MB

    ssm_gen<<<dim3(HH, 2), 256, 0, stream>>>(A_re0, A_im0, C_re0, C_im0, log_dt0, kc1);
    ssm_gen<<<dim3(HH, 2), 256, 0, stream>>>(A_re1, A_im1, C_re1, C_im1, log_dt1, kc2);
    convY<<<dim3(4, 2*HH), 256, 0, stream>>>(u, kc2, wtb);
    convX<<<dim3(4, 2*HH), 256, 0, stream>>>(wtb, u, kc1, D, out);
}

// Round 4
// 91.701 us; speedup vs baseline: 3.5663x; 1.5575x over previous
//
#include <hip/hip_runtime.h>

#define HH 128
#define NN 64
#define LL 256
#define LP 512

typedef __attribute__((ext_vector_type(8))) short bf8;
typedef __attribute__((ext_vector_type(4))) float f32x4;

__device__ inline ushort f2bf(float f) {
    uint x = __float_as_uint(f);
    return (ushort)((x + 0x7fffu + ((x >> 16) & 1u)) >> 16);
}

// Generate concatenated bidirectional SSM kernels for BOTH axes in one launch.
// kcat[h][256+d] = kf[d]; kcat[h][255-l] = kb[l].
__global__ __launch_bounds__(256) void ssm_gen2(
    const float* __restrict__ A_re0, const float* __restrict__ A_im0,
    const float* __restrict__ C_re0, const float* __restrict__ C_im0,
    const float* __restrict__ log_dt0,
    const float* __restrict__ A_re1, const float* __restrict__ A_im1,
    const float* __restrict__ C_re1, const float* __restrict__ C_im1,
    const float* __restrict__ log_dt1,
    ushort* __restrict__ kc1, ushort* __restrict__ kc2)
{
    int l = threadIdx.x;
    int h = blockIdx.x;
    int c = blockIdx.y;
    int s = blockIdx.z;
    const float* A_re = s ? A_re1 : A_re0;
    const float* A_im = s ? A_im1 : A_im0;
    const float* C_re = s ? C_re1 : C_re0;
    const float* C_im = s ? C_im1 : C_im0;
    const float* ldt  = s ? log_dt1 : log_dt0;
    ushort* kcat      = s ? kc2 : kc1;

    float dt = expf(ldt[h]);
    float acc = 0.f;
    for (int n = 0; n < NN; ++n) {
        float ar = A_re[h*NN + n], ai = A_im[h*NN + n];
        float cr = C_re[(c*HH + h)*NN + n], ci = C_im[(c*HH + h)*NN + n];
        float xr = dt * ar, xi = dt * ai;
        float e = expf(xr);
        float sn, cs; sincosf(xi, &sn, &cs);
        float er = e*cs - 1.f, ei = e*sn;
        float inv = 1.f / (ar*ar + ai*ai);
        float dr = (er*ar + ei*ai) * inv;
        float di = (ei*ar - er*ai) * inv;
        float Kr = cr*dr - ci*di;
        float Ki = cr*di + ci*dr;
        float mag = expf(xr * (float)l);
        float s2, c2; sincosf(xi * (float)l, &s2, &c2);
        acc += Kr*(mag*c2) - Ki*(mag*s2);
    }
    int idx = (c == 0) ? (256 + l) : (255 - l);
    kcat[h*LP + idx] = f2bf(2.f * acc);
}

// Fused S4ND: per block computes Y[x' 0..255][y' half 128] for one (b,h).
// Phase 1: WT[y'][x] = sum_y M2[y'][y] * U[x][y]   (WT kept in LDS, bf16)
// Phase 2: Y[x'][y'] = sum_x M1[x'][x] * WT[y'][x] + D[h]*u[x'][y']
__global__ __launch_bounds__(512) void s4nd_fused(
    const float* __restrict__ u, const ushort* __restrict__ kc1,
    const ushort* __restrict__ kc2, const float* __restrict__ Dv,
    float* __restrict__ out)
{
    __shared__ ushort WT[128][264];          // 67584 B
    __shared__ ushort buf[15360];            // 30720 B (sM2+sU in ph1, sM1 in ph2)
    __shared__ ushort skc1[LP], skc2[LP];    // 2048 B

    ushort (*sM2)[40] = (ushort(*)[40])buf;            // [128][40]
    ushort (*sU )[40] = (ushort(*)[40])(buf + 5120);   // [256][40]
    ushort (*sM1)[40] = (ushort(*)[40])buf;            // [256][40]

    int bh = blockIdx.y;
    int h  = bh & (HH - 1);
    int y0 = blockIdx.x * 128;      // y' half offset
    int tid = threadIdx.x;
    int lane = tid & 63;
    int w = tid >> 6;
    int c = lane & 15, q = lane >> 4;

    skc1[tid] = kc1[h*LP + tid];
    skc2[tid] = kc2[h*LP + tid];

    const float* ub = u + (size_t)bh * LL * LL;

    // phase-1 wave layout: 2(m=y') x 4(n=x); phase-2: 4(m=x') x 2(n=y')
    int wm1 = (w >> 2) * 64, wn1 = (w & 3) * 64;
    int wm2 = (w >> 1) * 64, wn2 = (w & 1) * 64;

    f32x4 acc[4][4];
#pragma unroll
    for (int mi = 0; mi < 4; ++mi)
#pragma unroll
        for (int ni = 0; ni < 4; ++ni)
            acc[mi][ni] = (f32x4){0.f, 0.f, 0.f, 0.f};

    // staging indices (phase 1)
    int ur  = tid >> 1;            // u row 0..255
    int uh  = (tid & 1) * 16;      // col half
    int gr1 = tid >> 2;            // sM2 row 0..127
    int go1 = (tid & 3) * 8;       // sM2 col offset

    // prefetch u regs for kk=0
    float4 up0, up1, up2, up3;
    {
        const float* p = ub + (size_t)ur * LL + uh;
        up0 = ((const float4*)p)[0]; up1 = ((const float4*)p)[1];
        up2 = ((const float4*)p)[2]; up3 = ((const float4*)p)[3];
    }

    __syncthreads();   // skc visible

    for (int kk = 0; kk < 8; ++kk) {
        // write prefetched u tile -> sU (bf16)
        uint4 w0, w1;
        w0.x = (uint)f2bf(up0.x) | ((uint)f2bf(up0.y) << 16);
        w0.y = (uint)f2bf(up0.z) | ((uint)f2bf(up0.w) << 16);
        w0.z = (uint)f2bf(up1.x) | ((uint)f2bf(up1.y) << 16);
        w0.w = (uint)f2bf(up1.z) | ((uint)f2bf(up1.w) << 16);
        w1.x = (uint)f2bf(up2.x) | ((uint)f2bf(up2.y) << 16);
        w1.y = (uint)f2bf(up2.z) | ((uint)f2bf(up2.w) << 16);
        w1.z = (uint)f2bf(up3.x) | ((uint)f2bf(up3.y) << 16);
        w1.w = (uint)f2bf(up3.z) | ((uint)f2bf(up3.w) << 16);
        *(uint4*)&sU[ur][uh]     = w0;
        *(uint4*)&sU[ur][uh + 8] = w1;

        // generate M2 tile: sM2[r][yy] = skc2[256 + y0+r - kk*32 - yy]
        {
            int base = 256 + y0 + gr1 - kk*32 - go1;
#pragma unroll
            for (int j = 0; j < 4; ++j) {
                uint lo = skc2[base - 2*j];
                uint hi = skc2[base - 2*j - 1];
                *(uint*)&sM2[gr1][go1 + 2*j] = lo | (hi << 16);
            }
        }

        // prefetch next k-step's u tile (latency hidden under barrier+mfma)
        if (kk < 7) {
            const float* p = ub + (size_t)ur * LL + (kk + 1)*32 + uh;
            up0 = ((const float4*)p)[0]; up1 = ((const float4*)p)[1];
            up2 = ((const float4*)p)[2]; up3 = ((const float4*)p)[3];
        }

        __syncthreads();

        bf8 a[4], b[4];
#pragma unroll
        for (int mi = 0; mi < 4; ++mi)
            a[mi] = *(const bf8*)&sM2[wm1 + 16*mi + c][8*q];
#pragma unroll
        for (int ni = 0; ni < 4; ++ni)
            b[ni] = *(const bf8*)&sU[wn1 + 16*ni + c][8*q];
#pragma unroll
        for (int mi = 0; mi < 4; ++mi)
#pragma unroll
            for (int ni = 0; ni < 4; ++ni)
                acc[mi][ni] = __builtin_amdgcn_mfma_f32_16x16x32_bf16(a[mi], b[ni], acc[mi][ni], 0, 0, 0);

        __syncthreads();
    }

    // phase-1 epilogue: acc -> WT (bf16), reset acc
#pragma unroll
    for (int mi = 0; mi < 4; ++mi)
#pragma unroll
        for (int ni = 0; ni < 4; ++ni)
#pragma unroll
            for (int r = 0; r < 4; ++r) {
                WT[wm1 + 16*mi + 4*q + r][wn1 + 16*ni + c] = f2bf(acc[mi][ni][r]);
                acc[mi][ni][r] = 0.f;
            }
    __syncthreads();

    // phase 2
    int gr2 = tid >> 1;            // sM1 row 0..255
    int go2 = (tid & 1) * 16;

    for (int kk = 0; kk < 8; ++kk) {
        int xb = kk * 32;
        {
            int base = 256 + gr2 - xb - go2;
#pragma unroll
            for (int j = 0; j < 8; ++j) {
                uint lo = skc1[base - 2*j];
                uint hi = skc1[base - 2*j - 1];
                *(uint*)&sM1[gr2][go2 + 2*j] = lo | (hi << 16);
            }
        }
        __syncthreads();

        bf8 a[4], b[4];
#pragma unroll
        for (int mi = 0; mi < 4; ++mi)
            a[mi] = *(const bf8*)&sM1[wm2 + 16*mi + c][8*q];
#pragma unroll
        for (int ni = 0; ni < 4; ++ni)
            b[ni] = *(const bf8*)&WT[wn2 + 16*ni + c][xb + 8*q];
#pragma unroll
        for (int mi = 0; mi < 4; ++mi)
#pragma unroll
            for (int ni = 0; ni < 4; ++ni)
                acc[mi][ni] = __builtin_amdgcn_mfma_f32_16x16x32_bf16(a[mi], b[ni], acc[mi][ni], 0, 0, 0);

        __syncthreads();
    }

    // epilogue: Y + D*u -> global
    float dh = Dv[h];
    float* yb_ = out + (size_t)bh * LL * LL;
#pragma unroll
    for (int mi = 0; mi < 4; ++mi)
#pragma unroll
        for (int ni = 0; ni < 4; ++ni)
#pragma unroll
            for (int r = 0; r < 4; ++r) {
                int row = wm2 + 16*mi + 4*q + r;        // x'
                int col = y0 + wn2 + 16*ni + c;         // y'
                size_t o = (size_t)row * LL + col;
                yb_[o] = acc[mi][ni][r] + dh * ub[o];
            }
}

extern "C" void kernel_launch(void* const* d_in, const int* in_sizes, int n_in,
                              void* d_out, int out_size, void* d_ws, size_t ws_size,
                              hipStream_t stream)
{
    const float* u       = (const float*)d_in[0];
    const float* D       = (const float*)d_in[1];
    const float* A_re0   = (const float*)d_in[2];
    const float* A_im0   = (const float*)d_in[3];
    const float* C_re0   = (const float*)d_in[4];
    const float* C_im0   = (const float*)d_in[5];
    const float* log_dt0 = (const float*)d_in[6];
    const float* A_re1   = (const float*)d_in[7];
    const float* A_im1   = (const float*)d_in[8];
    const float* C_re1   = (const float*)d_in[9];
    const float* C_im1   = (const float*)d_in[10];
    const float* log_dt1 = (const float*)d_in[11];
    float* out = (float*)d_out;

    ushort* kc1 = (ushort*)d_ws;          // 128*512 ushorts
    ushort* kc2 = kc1 + HH*LP;            // 128*512 ushorts

    ssm_gen2<<<dim3(HH, 2, 2), 256, 0, stream>>>(
        A_re0, A_im0, C_re0, C_im0, log_dt0,
        A_re1, A_im1, C_re1, C_im1, log_dt1, kc1, kc2);
    s4nd_fused<<<dim3(2, 2*HH), 512, 0, stream>>>(u, kc1, kc2, D, out);
}

// Round 5
// 61.097 us; speedup vs baseline: 5.3527x; 1.5009x over previous
//
#include <hip/hip_runtime.h>

#define HH 128
#define NN 64
#define LL 256
#define WPITCH 264   // u16 per WT row (132 words)

typedef __attribute__((ext_vector_type(8))) short bf8;
typedef __attribute__((ext_vector_type(4))) float f32x4;

__device__ inline ushort f2bf(float f) {
    uint x = __float_as_uint(f);
    return (ushort)((x + 0x7fffu + ((x >> 16) & 1u)) >> 16);
}
__device__ inline uint cvt_pk_bf16(float lo, float hi) {
    uint r;
    asm volatile("v_cvt_pk_bf16_f32 %0, %1, %2" : "=v"(r) : "v"(lo), "v"(hi));
    return r;
}
#define MFMA(a,b,c) __builtin_amdgcn_mfma_f32_16x16x32_bf16((a),(b),(c),0,0,0)

// One fused kernel per (b,h,y-half): generates both SSM kernels in-block,
// phase 1: WT[y'][x] = sum_y M2[y'][y]*U[x][y] (acc in regs, WT in LDS),
// phase 2: Y[x'][y'] = sum_x M1[x'][x]*WT[y'][x] + D[h]*u  -> global.
__global__ __launch_bounds__(512, 4) void s4nd_one(
    const float* __restrict__ u, const float* __restrict__ Dv,
    const float* __restrict__ A_re0, const float* __restrict__ A_im0,
    const float* __restrict__ C_re0, const float* __restrict__ C_im0,
    const float* __restrict__ log_dt0,
    const float* __restrict__ A_re1, const float* __restrict__ A_im1,
    const float* __restrict__ C_re1, const float* __restrict__ C_im1,
    const float* __restrict__ log_dt1,
    float* __restrict__ out)
{
    __shared__ ushort WT[128 * WPITCH];   // 67584 B
    __shared__ float4 par[256];           // 4096 B : (s,ch,n) -> {xr, xi_rev, Kr2, Ki2}
    __shared__ ushort rev[2][512];        // 2048 B : rev[s][i] = kcat_s[511-i]
    __shared__ uint   arr[2][512];        // 4096 B : arr[s][i] = rev[i] | rev[i+1]<<16

    int tid = threadIdx.x;
    int bh  = blockIdx.y;
    int h   = bh & (HH - 1);
    int y0  = blockIdx.x * 128;

    // ---- SSM param precompute: 256 threads, one (s,ch,n) each ----
    if (tid < 256) {
        int n  = tid & 63;
        int ch = (tid >> 6) & 1;
        int s  = tid >> 7;
        const float* Ar = s ? A_re1 : A_re0;
        const float* Ai = s ? A_im1 : A_im0;
        const float* Cr = s ? C_re1 : C_re0;
        const float* Ci = s ? C_im1 : C_im0;
        const float* Ld = s ? log_dt1 : log_dt0;
        float dt = __expf(Ld[h]);
        float ar = Ar[h*NN + n], ai = Ai[h*NN + n];
        float cr = Cr[(ch*HH + h)*NN + n], ci = Ci[(ch*HH + h)*NN + n];
        float xr = dt * ar, xi = dt * ai;
        // exp(i*xi) via hw trig (xi_rev small here, fract-safe)
        float phr = xi * 0.15915494f;
        float phf = phr - floorf(phr);
        float sn = __sinf(6.2831853f * phf);
        float cs = __cosf(6.2831853f * phf);
        float e  = __expf(xr);
        float er = e*cs - 1.f, ei = e*sn;
        float inv = 1.f / (ar*ar + ai*ai);
        float dr = (er*ar + ei*ai) * inv;
        float di = (ei*ar - er*ai) * inv;
        float Kr = 2.f*(cr*dr - ci*di);
        float Ki = 2.f*(cr*di + ci*dr);
        par[tid] = (float4){ xr, xi * 0.15915494f, Kr, Ki };
    }
    __syncthreads();

    // ---- tap generation: thread (ch,l) computes one tap of each kernel ----
    {
        int l  = tid & 255;
        int ch = tid >> 8;
        float lf = (float)l;
        int ri = ch ? (256 + l) : (255 - l);
#pragma unroll
        for (int s = 0; s < 2; ++s) {
            const float4* pb = &par[s*128 + ch*64];
            float acc = 0.f;
            for (int n = 0; n < NN; ++n) {
                float4 p = pb[n];
                float mag = __expf(p.x * lf);
                float ph  = p.y * lf;
                float phf = ph - floorf(ph);
                float ang = 6.2831853f * phf;
                acc += p.z * (mag * __cosf(ang)) - p.w * (mag * __sinf(ang));
            }
            rev[s][ri] = f2bf(acc);
        }
    }
    __syncthreads();
    if (tid < 511) {
        arr[0][tid] = (uint)rev[0][tid] | ((uint)rev[0][tid+1] << 16);
        arr[1][tid] = (uint)rev[1][tid] | ((uint)rev[1][tid+1] << 16);
    }
    __syncthreads();

    int lane = tid & 63;
    int w = tid >> 6;                 // 0..7
    int c = lane & 15, q = lane >> 4;

    f32x4 acc[16];
#pragma unroll
    for (int i = 0; i < 16; ++i) acc[i] = (f32x4){0.f,0.f,0.f,0.f};

    const float* ub = u + (size_t)bh * LL * LL;

    // ---- phase 1 (no barriers): wave w covers x in [w*32, w*32+32), y' = y0..y0+127 ----
    // acc[mi*2+ni]: mi = y'-block (16 rows each, 8 blocks), ni = x-block (16 cols, 2 blocks)
    {
        const float* up0 = ub + (size_t)(w*32 + c) * LL;
        const float* up1 = ub + (size_t)(w*32 + 16 + c) * LL;
#pragma unroll 2
        for (int kk = 0; kk < 8; ++kk) {
            int yb = kk*32 + 8*q;
            float4 f0 = *(const float4*)(up0 + yb);
            float4 f1 = *(const float4*)(up0 + yb + 4);
            float4 f2 = *(const float4*)(up1 + yb);
            float4 f3 = *(const float4*)(up1 + yb + 4);
            bf8 b0, b1;
            uint* pb0 = (uint*)&b0; uint* pb1 = (uint*)&b1;
            pb0[0] = cvt_pk_bf16(f0.x, f0.y); pb0[1] = cvt_pk_bf16(f0.z, f0.w);
            pb0[2] = cvt_pk_bf16(f1.x, f1.y); pb0[3] = cvt_pk_bf16(f1.z, f1.w);
            pb1[0] = cvt_pk_bf16(f2.x, f2.y); pb1[1] = cvt_pk_bf16(f2.z, f2.w);
            pb1[2] = cvt_pk_bf16(f3.x, f3.y); pb1[3] = cvt_pk_bf16(f3.z, f3.w);
            int sbase = 255 - y0 - c + kk*32 + 8*q;
#pragma unroll
            for (int mi = 0; mi < 8; ++mi) {
                int s0 = sbase - 16*mi;   // a[j] = M2[y0+16mi+c][kk*32+8q+j]
                bf8 a; uint* pa = (uint*)&a;
                pa[0] = arr[1][s0];     pa[1] = arr[1][s0 + 2];
                pa[2] = arr[1][s0 + 4]; pa[3] = arr[1][s0 + 6];
                acc[mi*2 + 0] = MFMA(a, b0, acc[mi*2 + 0]);
                acc[mi*2 + 1] = MFMA(a, b1, acc[mi*2 + 1]);
            }
        }
    }

    // ---- acc -> WT (bf16, T2 XOR-swizzled columns) ----
#pragma unroll
    for (int mi = 0; mi < 8; ++mi)
#pragma unroll
        for (int ni = 0; ni < 2; ++ni)
#pragma unroll
            for (int r = 0; r < 4; ++r) {
                int row = 16*mi + 4*q + r;
                int col = (w*32 + 16*ni + c) ^ ((row & 7) << 3);
                WT[row*WPITCH + col] = f2bf(acc[mi*2 + ni][r]);
                acc[mi*2 + ni][r] = 0.f;
            }
    __syncthreads();

    // ---- phase 2 (no barriers): wave w -> x' block wm2, y' block wn2 ----
    {
        int wm2 = (w >> 1) * 64, wn2 = (w & 1) * 64;
#pragma unroll
        for (int kk = 0; kk < 8; ++kk) {
            int xb = kk*32;
            bf8 b[4];
#pragma unroll
            for (int ni = 0; ni < 4; ++ni) {
                int row = wn2 + 16*ni + c;
                int col = (xb + 8*q) ^ ((row & 7) << 3);
                b[ni] = *(const bf8*)&WT[row*WPITCH + col];
            }
            int sbase = 255 - wm2 - c + xb + 8*q;
#pragma unroll
            for (int mi = 0; mi < 4; ++mi) {
                int s0 = sbase - 16*mi;  // a[j] = M1[wm2+16mi+c][xb+8q+j]
                bf8 a; uint* pa = (uint*)&a;
                pa[0] = arr[0][s0];     pa[1] = arr[0][s0 + 2];
                pa[2] = arr[0][s0 + 4]; pa[3] = arr[0][s0 + 6];
#pragma unroll
                for (int ni = 0; ni < 4; ++ni)
                    acc[mi*4 + ni] = MFMA(a, b[ni], acc[mi*4 + ni]);
            }
        }

        // ---- epilogue: Y + D*u -> global ----
        float dh = Dv[h];
        float* yb_ = out + (size_t)bh * LL * LL;
#pragma unroll
        for (int mi = 0; mi < 4; ++mi)
#pragma unroll
            for (int ni = 0; ni < 4; ++ni)
#pragma unroll
                for (int r = 0; r < 4; ++r) {
                    int row = wm2 + 16*mi + 4*q + r;
                    int col = y0 + wn2 + 16*ni + c;
                    size_t o = (size_t)row * LL + col;
                    yb_[o] = acc[mi*4 + ni][r] + dh * ub[o];
                }
    }
}

extern "C" void kernel_launch(void* const* d_in, const int* in_sizes, int n_in,
                              void* d_out, int out_size, void* d_ws, size_t ws_size,
                              hipStream_t stream)
{
    const float* u       = (const float*)d_in[0];
    const float* D       = (const float*)d_in[1];
    const float* A_re0   = (const float*)d_in[2];
    const float* A_im0   = (const float*)d_in[3];
    const float* C_re0   = (const float*)d_in[4];
    const float* C_im0   = (const float*)d_in[5];
    const float* log_dt0 = (const float*)d_in[6];
    const float* A_re1   = (const float*)d_in[7];
    const float* A_im1   = (const float*)d_in[8];
    const float* C_re1   = (const float*)d_in[9];
    const float* C_im1   = (const float*)d_in[10];
    const float* log_dt1 = (const float*)d_in[11];
    float* out = (float*)d_out;

    s4nd_one<<<dim3(2, 2*HH), 512, 0, stream>>>(
        u, D,
        A_re0, A_im0, C_re0, C_im0, log_dt0,
        A_re1, A_im1, C_re1, C_im1, log_dt1,
        out);
}

// Round 6
// 54.645 us; speedup vs baseline: 5.9848x; 1.1181x over previous
//
#include <hip/hip_runtime.h>

#define HH 128
#define NN 64
#define LL 256
#define WPITCH 264   // u16 per WT row (132 words)

typedef __attribute__((ext_vector_type(8))) short bf8;
typedef __attribute__((ext_vector_type(4))) float f32x4;

__device__ inline ushort f2bf(float f) {
    uint x = __float_as_uint(f);
    return (ushort)((x + 0x7fffu + ((x >> 16) & 1u)) >> 16);
}
__device__ inline uint cvt_pk_bf16(float lo, float hi) {
    uint r;
    asm volatile("v_cvt_pk_bf16_f32 %0, %1, %2" : "=v"(r) : "v"(lo), "v"(hi));
    return r;
}
#define MFMA(a,b,c) __builtin_amdgcn_mfma_f32_16x16x32_bf16((a),(b),(c),0,0,0)

// Standalone tap generation with hw trig. Writes packed pair-table:
// arrg[(s*HH+h)*512 + i] = rev[i] | rev[i+1]<<16, rev[i] = kcat_s[h][511-i].
__global__ __launch_bounds__(512) void ssm_gen_fast(
    const float* __restrict__ A_re0, const float* __restrict__ A_im0,
    const float* __restrict__ C_re0, const float* __restrict__ C_im0,
    const float* __restrict__ log_dt0,
    const float* __restrict__ A_re1, const float* __restrict__ A_im1,
    const float* __restrict__ C_re1, const float* __restrict__ C_im1,
    const float* __restrict__ log_dt1,
    uint* __restrict__ arrg)
{
    __shared__ float4 par[256];     // (s,ch,n) -> {xr, xi_rev, Kr2, Ki2}
    __shared__ ushort rev[2][512];

    int tid = threadIdx.x;
    int h   = blockIdx.x;

    if (tid < 256) {
        int n  = tid & 63;
        int ch = (tid >> 6) & 1;
        int s  = tid >> 7;
        const float* Ar = s ? A_re1 : A_re0;
        const float* Ai = s ? A_im1 : A_im0;
        const float* Cr = s ? C_re1 : C_re0;
        const float* Ci = s ? C_im1 : C_im0;
        const float* Ld = s ? log_dt1 : log_dt0;
        float dt = __expf(Ld[h]);
        float ar = Ar[h*NN + n], ai = Ai[h*NN + n];
        float cr = Cr[(ch*HH + h)*NN + n], ci = Ci[(ch*HH + h)*NN + n];
        float xr = dt * ar, xi = dt * ai;
        float phr = xi * 0.15915494f;
        float phf = phr - floorf(phr);
        float sn = __sinf(6.2831853f * phf);
        float cs = __cosf(6.2831853f * phf);
        float e  = __expf(xr);
        float er = e*cs - 1.f, ei = e*sn;
        float inv = 1.f / (ar*ar + ai*ai);
        float dr = (er*ar + ei*ai) * inv;
        float di = (ei*ar - er*ai) * inv;
        float Kr = 2.f*(cr*dr - ci*di);
        float Ki = 2.f*(cr*di + ci*dr);
        par[tid] = (float4){ xr, xi * 0.15915494f, Kr, Ki };
    }
    __syncthreads();

    {
        int l  = tid & 255;
        int ch = tid >> 8;
        float lf = (float)l;
        int ri = ch ? (256 + l) : (255 - l);
#pragma unroll
        for (int s = 0; s < 2; ++s) {
            const float4* pb = &par[s*128 + ch*64];
            float acc = 0.f;
            for (int n = 0; n < NN; ++n) {
                float4 p = pb[n];
                float mag = __expf(p.x * lf);
                float ph  = p.y * lf;
                float phf = ph - floorf(ph);
                float ang = 6.2831853f * phf;
                acc += p.z * (mag * __cosf(ang)) - p.w * (mag * __sinf(ang));
            }
            rev[s][ri] = f2bf(acc);
        }
    }
    __syncthreads();

#pragma unroll
    for (int s = 0; s < 2; ++s) {
        uint lo = rev[s][tid];
        uint hi = (tid < 511) ? (uint)rev[s][tid + 1] : 0u;
        arrg[(s*HH + h)*512 + tid] = lo | (hi << 16);
    }
}

// Fused S4ND per (b,h,y-half):
// phase 1: WT[y'][x] = sum_y M2[y'][y]*U[x][y]  (acc in regs, WT in LDS)
// phase 2: Y[x'][y'] = sum_x M1[x'][x]*WT[y'][x] + D[h]*u -> global.
__global__ __launch_bounds__(512, 4) void s4nd_one(
    const float* __restrict__ u, const float* __restrict__ Dv,
    const uint* __restrict__ arrg, float* __restrict__ out)
{
    __shared__ ushort WT[128 * WPITCH];   // 67584 B
    __shared__ uint   arr[2][512];        // 4096 B

    int tid = threadIdx.x;

    // XCD-pairing swizzle: both y-halves of a bh land on the same XCD,
    // temporally adjacent -> u tile L2-shared between them.
    int j    = blockIdx.x;
    int xcd  = j & 7;
    int k    = j >> 3;
    int bh   = xcd * 32 + (k >> 1);
    int y0   = (k & 1) * 128;
    int h    = bh & (HH - 1);

    arr[0][tid] = arrg[h*512 + tid];
    arr[1][tid] = arrg[(HH + h)*512 + tid];
    __syncthreads();

    int lane = tid & 63;
    int w = tid >> 6;                 // 0..7
    int c = lane & 15, q = lane >> 4;

    f32x4 acc[16];
#pragma unroll
    for (int i = 0; i < 16; ++i) acc[i] = (f32x4){0.f,0.f,0.f,0.f};

    const float* ub = u + (size_t)bh * LL * LL;

    // ---- phase 1 (no barriers): wave w covers x in [w*32, w*32+32) ----
    {
        const float* up0 = ub + (size_t)(w*32 + c) * LL;
        const float* up1 = ub + (size_t)(w*32 + 16 + c) * LL;
#pragma unroll 2
        for (int kk = 0; kk < 8; ++kk) {
            int yb = kk*32 + 8*q;
            float4 f0 = *(const float4*)(up0 + yb);
            float4 f1 = *(const float4*)(up0 + yb + 4);
            float4 f2 = *(const float4*)(up1 + yb);
            float4 f3 = *(const float4*)(up1 + yb + 4);
            bf8 b0, b1;
            uint* pb0 = (uint*)&b0; uint* pb1 = (uint*)&b1;
            pb0[0] = cvt_pk_bf16(f0.x, f0.y); pb0[1] = cvt_pk_bf16(f0.z, f0.w);
            pb0[2] = cvt_pk_bf16(f1.x, f1.y); pb0[3] = cvt_pk_bf16(f1.z, f1.w);
            pb1[0] = cvt_pk_bf16(f2.x, f2.y); pb1[1] = cvt_pk_bf16(f2.z, f2.w);
            pb1[2] = cvt_pk_bf16(f3.x, f3.y); pb1[3] = cvt_pk_bf16(f3.z, f3.w);
            int sbase = 255 - y0 - c + kk*32 + 8*q;
            __builtin_amdgcn_s_setprio(1);
#pragma unroll
            for (int mi = 0; mi < 8; ++mi) {
                int s0 = sbase - 16*mi;   // a[j] = M2[y0+16mi+c][kk*32+8q+j]
                bf8 a; uint* pa = (uint*)&a;
                pa[0] = arr[1][s0];     pa[1] = arr[1][s0 + 2];
                pa[2] = arr[1][s0 + 4]; pa[3] = arr[1][s0 + 6];
                acc[mi*2 + 0] = MFMA(a, b0, acc[mi*2 + 0]);
                acc[mi*2 + 1] = MFMA(a, b1, acc[mi*2 + 1]);
            }
            __builtin_amdgcn_s_setprio(0);
        }
    }

    // ---- acc -> WT (bf16, XOR-swizzled columns) ----
#pragma unroll
    for (int mi = 0; mi < 8; ++mi)
#pragma unroll
        for (int ni = 0; ni < 2; ++ni)
#pragma unroll
            for (int r = 0; r < 4; ++r) {
                int row = 16*mi + 4*q + r;
                int col = (w*32 + 16*ni + c) ^ ((row & 7) << 3);
                WT[row*WPITCH + col] = f2bf(acc[mi*2 + ni][r]);
                acc[mi*2 + ni][r] = 0.f;
            }
    __syncthreads();

    // ---- phase 2 (no barriers): wave w -> x' block wm2, y' block wn2 ----
    {
        int wm2 = (w >> 1) * 64, wn2 = (w & 1) * 64;
#pragma unroll
        for (int kk = 0; kk < 8; ++kk) {
            int xb = kk*32;
            bf8 b[4];
#pragma unroll
            for (int ni = 0; ni < 4; ++ni) {
                int row = wn2 + 16*ni + c;
                int col = (xb + 8*q) ^ ((row & 7) << 3);
                b[ni] = *(const bf8*)&WT[row*WPITCH + col];
            }
            int sbase = 255 - wm2 - c + xb + 8*q;
            __builtin_amdgcn_s_setprio(1);
#pragma unroll
            for (int mi = 0; mi < 4; ++mi) {
                int s0 = sbase - 16*mi;  // a[j] = M1[wm2+16mi+c][xb+8q+j]
                bf8 a; uint* pa = (uint*)&a;
                pa[0] = arr[0][s0];     pa[1] = arr[0][s0 + 2];
                pa[2] = arr[0][s0 + 4]; pa[3] = arr[0][s0 + 6];
#pragma unroll
                for (int ni = 0; ni < 4; ++ni)
                    acc[mi*4 + ni] = MFMA(a, b[ni], acc[mi*4 + ni]);
            }
            __builtin_amdgcn_s_setprio(0);
        }

        // ---- epilogue: Y + D*u -> global ----
        float dh = Dv[h];
        float* yb_ = out + (size_t)bh * LL * LL;
#pragma unroll
        for (int mi = 0; mi < 4; ++mi)
#pragma unroll
            for (int ni = 0; ni < 4; ++ni)
#pragma unroll
                for (int r = 0; r < 4; ++r) {
                    int row = wm2 + 16*mi + 4*q + r;
                    int col = y0 + wn2 + 16*ni + c;
                    size_t o = (size_t)row * LL + col;
                    yb_[o] = acc[mi*4 + ni][r] + dh * ub[o];
                }
    }
}

extern "C" void kernel_launch(void* const* d_in, const int* in_sizes, int n_in,
                              void* d_out, int out_size, void* d_ws, size_t ws_size,
                              hipStream_t stream)
{
    const float* u       = (const float*)d_in[0];
    const float* D       = (const float*)d_in[1];
    const float* A_re0   = (const float*)d_in[2];
    const float* A_im0   = (const float*)d_in[3];
    const float* C_re0   = (const float*)d_in[4];
    const float* C_im0   = (const float*)d_in[5];
    const float* log_dt0 = (const float*)d_in[6];
    const float* A_re1   = (const float*)d_in[7];
    const float* A_im1   = (const float*)d_in[8];
    const float* C_re1   = (const float*)d_in[9];
    const float* C_im1   = (const float*)d_in[10];
    const float* log_dt1 = (const float*)d_in[11];
    float* out = (float*)d_out;

    uint* arrg = (uint*)d_ws;   // 2*128*512 u32 = 512 KB

    ssm_gen_fast<<<HH, 512, 0, stream>>>(
        A_re0, A_im0, C_re0, C_im0, log_dt0,
        A_re1, A_im1, C_re1, C_im1, log_dt1, arrg);
    s4nd_one<<<512, 512, 0, stream>>>(u, D, arrg, out);
}